// Round 5
// baseline (437.087 us; speedup 1.0000x reference)
//
#include <hip/hip_runtime.h>
#include <hip/hip_bf16.h>

// Problem constants
#define BB 16384
#define LL 9
#define DD 32
#define CR 128

typedef float v2 __attribute__((ext_vector_type(2)));

// ws float layout (LDS image, 10368 floats):
//   [0..8191]     AB: (d*64 + (c&63))*4 + slot, slot = {0:A1 c<64, 1:A1 c>=64,
//                 2:A2 c<64, 3:A2 c>=64};  A1 = Wi@W1, A2 = Wj@W1
//   [8192..10367] WK: 8192 + k*128 + (c&63)*2 + (c>>6)
//                 WK[k][c] = sum_e (rv_k[e]+bi+bj+br)[e]*W1[e][c] + b1[c],
//                 rv_k = relpos_row(i-j=k-8) @ Wr

__global__ void precomp_kernel(const float* __restrict__ relpos,
                               const float* __restrict__ Wi, const float* __restrict__ bi,
                               const float* __restrict__ Wj, const float* __restrict__ bj,
                               const float* __restrict__ Wr, const float* __restrict__ br,
                               const float* __restrict__ W1, const float* __restrict__ b1,
                               float* __restrict__ ws)
{
    const int tid = threadIdx.x;
    const int blk = blockIdx.x;           // 0..40
    if (blk < DD) {
        // A tables: one d per block; 256 threads cover A1[128 c] + A2[128 c]
        const int d = blk;
        const int c = tid & 127;
        const int which = tid >> 7;       // 0 = A1 (Wi), 1 = A2 (Wj)
        const float* W = which ? Wj : Wi;
        float s = 0.f;
        #pragma unroll
        for (int e = 0; e < DD; ++e) s = fmaf(W[d * DD + e], W1[e * CR + c], s);
        ws[(d * 64 + (c & 63)) * 4 + which * 2 + (c >> 6)] = s;
    } else {
        // WK: blocks 32..40, block q handles k = 2q, 2q+1 (block 40: k=16 only)
        const int q = blk - DD;
        __shared__ float rv2[2][DD];
        const int nk = (q < 8) ? 2 : 1;
        if (tid < 64) {
            const int kk = tid >> 5;
            const int e = tid & 31;
            if (kk < nk) {
                const int k = q * 2 + kk;
                const int dk = k - 8;
                const int i = dk > 0 ? dk : 0;
                const int j = i - dk;
                float s = bi[e] + bj[e] + br[e];
                #pragma unroll
                for (int d = 0; d < DD; ++d)
                    s = fmaf(relpos[(i * LL + j) * DD + d], Wr[d * DD + e], s);
                rv2[kk][e] = s;
            }
        }
        __syncthreads();
        const int kk = tid >> 7;
        const int c = tid & 127;
        if (kk < nk) {
            const int k = q * 2 + kk;
            float s = b1[c];
            #pragma unroll
            for (int e = 0; e < DD; ++e) s = fmaf(rv2[kk][e], W1[e * CR + c], s);
            ws[8192 + k * 128 + (c & 63) * 2 + (c >> 6)] = s;
        }
    }
}

// Main: 4 waves/block, 4 batches/wave (2 pairs). Lane owns channels (c=lane, c+64)
// as a v2. seq goes global->VGPR->LDS (vector loads, vmcnt pipe), GEMV broadcasts
// it via uniform ds_read_b128. Tables in LDS, each table read shared by the pair.
__global__ __launch_bounds__(256, 3)
void outersum_main(const float* __restrict__ seq,
                   const float* __restrict__ ws,
                   const float* __restrict__ W2,
                   const float* __restrict__ b2,
                   float* __restrict__ out)
{
    __shared__ float lds[10368 + 4 * 576];     // 49.5 KB: AB+WK image, 4 wave seq buffers
    float* AB  = lds;
    float* WKl = lds + 8192;
    const int tid = threadIdx.x;

    // Stage the 10368-float table image: 2592 float4, straight copy.
    {
        const float4* s4 = (const float4*)ws;
        float4* d4 = (float4*)lds;
        #pragma unroll
        for (int r = 0; r < 10; ++r) d4[tid + r * 256] = s4[tid + r * 256];
        if (tid < 32) d4[tid + 2560] = s4[tid + 2560];
    }
    __syncthreads();

    const int lane = tid & 63;
    const int wave = tid >> 6;
    float* SEQ = lds + 10368 + wave * 576;     // one pair buffer (2 batches = 576 f)

    const float2 w2a = ((const float2*)W2)[lane];
    const float2 w2b = ((const float2*)W2)[lane + 64];
    v2 w2o0; w2o0.x = w2a.x; w2o0.y = w2b.x;
    v2 w2o1; w2o1.x = w2a.y; w2o1.y = w2b.y;
    const float bias0 = 81.f * b2[0], bias1 = 81.f * b2[1];

    const int b0 = blockIdx.x * 16 + wave * 4;           // 4 batches per wave
    const float4* src0 = (const float4*)(seq + (size_t)b0 * 288);  // pair0: 144 f4
    const float4* src1 = src0 + 144;                               // pair1

    // Prologue: stage pair0 into LDS (lane-parallel vector loads).
    {
        float4 a = src0[lane], b = src0[lane + 64];
        *(float4*)&SEQ[lane * 4] = a;
        *(float4*)&SEQ[(lane + 64) * 4] = b;
        if (lane < 16) {
            float4 cc = src0[lane + 128];
            *(float4*)&SEQ[(lane + 128) * 4] = cc;
        }
    }
    // Issue pair1 loads early; held in regs while pair0 computes (T14 split).
    float4 p1a = src1[lane], p1b = src1[lane + 64];
    float4 p1c;
    if (lane < 16) p1c = src1[lane + 128];

    #pragma unroll
    for (int p = 0; p < 2; ++p) {
        // ---- GEMV for the pair: U/V for both batches ----
        v2 U0[LL], V0[LL], U1[LL], V1[LL];
        #pragma unroll
        for (int i = 0; i < LL; ++i) {
            U0[i] = (v2)0.f; V0[i] = (v2)0.f;
            U1[i] = (v2)0.f; V1[i] = (v2)0.f;
        }
        const float* sq0 = SEQ;
        const float* sq1 = SEQ + 288;
        #pragma unroll
        for (int dc = 0; dc < 8; ++dc) {
            float4 av0 = *(const float4*)&AB[((dc * 4 + 0) * 64 + lane) * 4];
            float4 av1 = *(const float4*)&AB[((dc * 4 + 1) * 64 + lane) * 4];
            float4 av2 = *(const float4*)&AB[((dc * 4 + 2) * 64 + lane) * 4];
            float4 av3 = *(const float4*)&AB[((dc * 4 + 3) * 64 + lane) * 4];
            #pragma unroll
            for (int i = 0; i < LL; ++i) {
                const float4 s0 = *(const float4*)&sq0[i * DD + dc * 4];  // uniform bcast
                const float4 s1 = *(const float4*)&sq1[i * DD + dc * 4];  // uniform bcast
                v2 t;
                t.x = av0.x; t.y = av0.y; U0[i] += (v2)(s0.x) * t; U1[i] += (v2)(s1.x) * t;
                t.x = av0.z; t.y = av0.w; V0[i] += (v2)(s0.x) * t; V1[i] += (v2)(s1.x) * t;
                t.x = av1.x; t.y = av1.y; U0[i] += (v2)(s0.y) * t; U1[i] += (v2)(s1.y) * t;
                t.x = av1.z; t.y = av1.w; V0[i] += (v2)(s0.y) * t; V1[i] += (v2)(s1.y) * t;
                t.x = av2.x; t.y = av2.y; U0[i] += (v2)(s0.z) * t; U1[i] += (v2)(s1.z) * t;
                t.x = av2.z; t.y = av2.w; V0[i] += (v2)(s0.z) * t; V1[i] += (v2)(s1.z) * t;
                t.x = av3.x; t.y = av3.y; U0[i] += (v2)(s0.w) * t; U1[i] += (v2)(s1.w) * t;
                t.x = av3.z; t.y = av3.w; V0[i] += (v2)(s0.w) * t; V1[i] += (v2)(s1.w) * t;
            }
        }

        // Pair0's seq reads are done: overwrite SEQ with pair1 (DS ops are in-order
        // per wave, and LDS writes overlap the outer phase below).
        if (p == 0) {
            *(float4*)&SEQ[lane * 4] = p1a;
            *(float4*)&SEQ[(lane + 64) * 4] = p1b;
            if (lane < 16) *(float4*)&SEQ[(lane + 128) * 4] = p1c;
        }

        // ---- Outer sum over diagonals k = i-j+8; wk read once per diagonal ----
        v2 acc00 = (v2)0.f, acc01 = (v2)0.f, acc10 = (v2)0.f, acc11 = (v2)0.f;
        #pragma unroll
        for (int k = 0; k < 17; ++k) {
            const v2 w = *(const v2*)&WKl[k * 128 + lane * 2];
            const int dk = k - 8;
            const int i0 = dk > 0 ? dk : 0;
            const int cnt = LL - (dk > 0 ? dk : -dk);
            #pragma unroll
            for (int t = 0; t < cnt; ++t) {
                const int i = i0 + t;
                const int j = i - dk;
                v2 t0 = U0[i] + V0[j] + w;
                t0.x = fmaxf(t0.x, 0.f); t0.y = fmaxf(t0.y, 0.f);
                acc00 += t0 * w2o0; acc01 += t0 * w2o1;
                v2 t1 = U1[i] + V1[j] + w;
                t1.x = fmaxf(t1.x, 0.f); t1.y = fmaxf(t1.y, 0.f);
                acc10 += t1 * w2o0; acc11 += t1 * w2o1;
            }
        }

        float r00 = acc00.x + acc00.y, r01 = acc01.x + acc01.y;
        float r10 = acc10.x + acc10.y, r11 = acc11.x + acc11.y;
        #pragma unroll
        for (int off = 32; off; off >>= 1) {
            r00 += __shfl_xor(r00, off, 64);
            r01 += __shfl_xor(r01, off, 64);
            r10 += __shfl_xor(r10, off, 64);
            r11 += __shfl_xor(r11, off, 64);
        }
        if (lane == 0) {
            const int bp = b0 + 2 * p;
            float4 o;
            o.x = r00 + bias0; o.y = r01 + bias1;
            o.z = r10 + bias0; o.w = r11 + bias1;
            *(float4*)(out + (size_t)bp * 2) = o;
        }
    }
}

extern "C" void kernel_launch(void* const* d_in, const int* in_sizes, int n_in,
                              void* d_out, int out_size, void* d_ws, size_t ws_size,
                              hipStream_t stream)
{
    const float* seq    = (const float*)d_in[0];
    const float* relpos = (const float*)d_in[1];
    const float* Wi     = (const float*)d_in[2];
    const float* bi     = (const float*)d_in[3];
    const float* Wj     = (const float*)d_in[4];
    const float* bj     = (const float*)d_in[5];
    const float* Wr     = (const float*)d_in[6];
    const float* br     = (const float*)d_in[7];
    const float* W1     = (const float*)d_in[8];
    const float* b1     = (const float*)d_in[9];
    const float* W2     = (const float*)d_in[10];
    const float* b2     = (const float*)d_in[11];
    float* out = (float*)d_out;
    float* ws  = (float*)d_ws;

    precomp_kernel<<<41, 256, 0, stream>>>(relpos, Wi, bi, Wj, bj, Wr, br, W1, b1, ws);

    // 1024 blocks x 4 waves, 16 batches/block; LDS 49.5 KB -> 3 blocks/CU,
    // launch_bounds(256,3) -> VGPR <= 168 so occupancy is LDS-limited, not VGPR.
    outersum_main<<<1024, 256, 0, stream>>>(seq, ws, W2, b2, out);
}

// Round 6
// 139.157 us; speedup vs baseline: 3.1410x; 3.1410x over previous
//
#include <hip/hip_runtime.h>
#include <hip/hip_bf16.h>

// Problem constants
#define BB 16384
#define LL 9
#define DD 32
#define CR 128

typedef float v2 __attribute__((ext_vector_type(2)));

// ws layout (floats): A1[32][128], A2[32][128], WK[17][128]
// A1 = Wi@W1, A2 = Wj@W1, WK[k] = (relpos_row_k@Wr + br + bi + bj)@W1 + b1

__global__ void precomp_kernel(const float* __restrict__ relpos,
                               const float* __restrict__ Wi, const float* __restrict__ bi,
                               const float* __restrict__ Wj, const float* __restrict__ bj,
                               const float* __restrict__ Wr, const float* __restrict__ br,
                               const float* __restrict__ W1, const float* __restrict__ b1,
                               float* __restrict__ ws)
{
    __shared__ float rv[DD];
    float* A1 = ws;
    float* A2 = ws + DD * CR;
    float* WK = ws + 2 * DD * CR;

    const int c = threadIdx.x;   // 0..127
    const int blk = blockIdx.x;  // 0..80

    if (blk < 32) {
        const int d = blk;
        float s = 0.f;
        #pragma unroll
        for (int e = 0; e < DD; ++e) s = fmaf(Wi[d * DD + e], W1[e * CR + c], s);
        A1[d * CR + c] = s;
    } else if (blk < 64) {
        const int d = blk - 32;
        float s = 0.f;
        #pragma unroll
        for (int e = 0; e < DD; ++e) s = fmaf(Wj[d * DD + e], W1[e * CR + c], s);
        A2[d * CR + c] = s;
    } else {
        const int k = blk - 64;       // 0..16, dk = k-8 = i-j
        const int dk = k - 8;
        const int i = dk > 0 ? dk : 0;
        const int j = i - dk;
        if (c < DD) {
            float s = bi[c] + bj[c] + br[c];
            #pragma unroll
            for (int d = 0; d < DD; ++d)
                s = fmaf(relpos[(i * LL + j) * DD + d], Wr[d * DD + c], s);
            rv[c] = s;
        }
        __syncthreads();
        float s = b1[c];
        #pragma unroll
        for (int e = 0; e < DD; ++e) s = fmaf(rv[e], W1[e * CR + c], s);
        WK[k * CR + c] = s;
    }
}

// R2 structure (proven: VGPR=112, tables register-resident, zero spill) with
// two fixes: (a) seq address laundered through a VGPR so the compiler emits
// vector global_load_dwordx4 (vmcnt pipe) instead of serialized s_loads;
// (b) 4096 waves (16/CU) for latency hiding.
__global__ __launch_bounds__(256)
void outersum_main(const float* __restrict__ seq,
                   const float* __restrict__ ws,
                   const float* __restrict__ W2,
                   const float* __restrict__ b2,
                   float* __restrict__ out)
{
    const float* gA1 = ws;
    const float* gA2 = ws + DD * CR;
    const float* gWK = ws + 2 * DD * CR;

    const int lane = threadIdx.x & 63;
    const int wave_id = blockIdx.x * 4 + (threadIdx.x >> 6);   // 0..4095
    const int cp = lane * 2;            // adjacent channel pair -> coalesced float2

    // Register-resident tables (packed): 64 + 17 v2 + W2.
    v2 a1[DD], a2[DD];
    #pragma unroll
    for (int d = 0; d < DD; ++d) {
        a1[d] = *(const v2*)(gA1 + d * CR + cp);
        a2[d] = *(const v2*)(gA2 + d * CR + cp);
    }
    v2 wk[17];
    #pragma unroll
    for (int k = 0; k < 17; ++k) wk[k] = *(const v2*)(gWK + k * CR + cp);

    const float4 w4 = *(const float4*)(W2 + 2 * cp);
    v2 w2o0; w2o0.x = w4.x; w2o0.y = w4.z;
    v2 w2o1; w2o1.x = w4.y; w2o1.y = w4.w;
    const float bias0 = 81.f * b2[0];
    const float bias1 = 81.f * b2[1];

    #pragma unroll 1
    for (int p = 0; p < 4; ++p) {
        const int b = wave_id * 4 + p;          // contiguous batches per wave
        // Launder the element offset into a VGPR: address becomes opaque ->
        // compiler emits global_load_dwordx4 (vector/vmcnt), not s_load.
        int off4 = b * 72;                      // float4 index of batch start
        asm volatile("" : "+v"(off4));
        const float4* sp4 = (const float4*)seq + off4;

        // ---- U/V GEMV: i-outer, float4 seq reads, pk-FMA vs register tables ----
        v2 U[LL], V[LL];
        #pragma unroll
        for (int i = 0; i < LL; ++i) {
            v2 u = (v2)0.f, v = (v2)0.f;
            #pragma unroll
            for (int dc = 0; dc < 8; ++dc) {
                const float4 s = sp4[i * 8 + dc];
                u += (v2)(s.x) * a1[dc * 4 + 0];
                v += (v2)(s.x) * a2[dc * 4 + 0];
                u += (v2)(s.y) * a1[dc * 4 + 1];
                v += (v2)(s.y) * a2[dc * 4 + 1];
                u += (v2)(s.z) * a1[dc * 4 + 2];
                v += (v2)(s.z) * a2[dc * 4 + 2];
                u += (v2)(s.w) * a1[dc * 4 + 3];
                v += (v2)(s.w) * a2[dc * 4 + 3];
            }
            U[i] = u; V[i] = v;
        }

        // ---- outer sum, static wk index k = i-j+8 ----
        v2 acc0 = (v2)0.f, acc1 = (v2)0.f;
        #pragma unroll
        for (int i = 0; i < LL; ++i) {
            #pragma unroll
            for (int j = 0; j < LL; ++j) {
                v2 t = U[i] + V[j] + wk[i - j + 8];
                t.x = fmaxf(t.x, 0.f);
                t.y = fmaxf(t.y, 0.f);
                acc0 += t * w2o0;
                acc1 += t * w2o1;
            }
        }

        float r0 = acc0.x + acc0.y;
        float r1 = acc1.x + acc1.y;
        #pragma unroll
        for (int offx = 32; offx; offx >>= 1) {
            r0 += __shfl_xor(r0, offx, 64);
            r1 += __shfl_xor(r1, offx, 64);
        }
        if (lane == 0) {
            float2 o; o.x = r0 + bias0; o.y = r1 + bias1;
            *(float2*)(out + (size_t)b * 2) = o;
        }
    }
}

extern "C" void kernel_launch(void* const* d_in, const int* in_sizes, int n_in,
                              void* d_out, int out_size, void* d_ws, size_t ws_size,
                              hipStream_t stream)
{
    const float* seq    = (const float*)d_in[0];
    const float* relpos = (const float*)d_in[1];
    const float* Wi     = (const float*)d_in[2];
    const float* bi     = (const float*)d_in[3];
    const float* Wj     = (const float*)d_in[4];
    const float* bj     = (const float*)d_in[5];
    const float* Wr     = (const float*)d_in[6];
    const float* br     = (const float*)d_in[7];
    const float* W1     = (const float*)d_in[8];
    const float* b1     = (const float*)d_in[9];
    const float* W2     = (const float*)d_in[10];
    const float* b2     = (const float*)d_in[11];
    float* out = (float*)d_out;
    float* ws  = (float*)d_ws;

    precomp_kernel<<<81, 128, 0, stream>>>(relpos, Wi, bi, Wj, bj, Wr, br, W1, b1, ws);

    // 1024 blocks x 4 waves = 4096 waves (16/CU target); 4 contiguous batches/wave.
    outersum_main<<<1024, 256, 0, stream>>>(seq, ws, W2, b2, out);
}